// Round 16
// baseline (189.328 us; speedup 1.0000x reference)
//
#include <hip/hip_runtime.h>
#include <hip/hip_bf16.h>
#include <math.h>

#define NN 512
#define CSD 384
#define CZ 128
#define HH 12
#define TMPW 1152          // 192 sq | 192 sk | 192 sv | 144 pq | 144 pk | 288 pv
#define CATH 176
#define CATDIM 2112
#define NSPLIT 6
#define KSPL 352

#define SW 0.14433756729740643f
#define PW 0.13608276348795434f
#define ZW 0.57735026918962576f
#define NEG_INF -3.4028234663852886e38f
#define MASK_NEG -1.0e30f

typedef float f32x4_t __attribute__((ext_vector_type(4)));
typedef short bf16x8_t __attribute__((ext_vector_type(8)));

union BFU { uint4 q; bf16x8_t v; ushort u[8]; };
union US4 { ushort us[4]; uint2 u2; };

static __device__ __forceinline__ ushort f2bf(float f) {
    __hip_bfloat16 h = __float2bfloat16(f);
    return *reinterpret_cast<ushort*>(&h);
}
static __device__ __forceinline__ float bf2f(ushort u) {
    unsigned int v = ((unsigned int)u) << 16;
    return __uint_as_float(v);
}

// ---------------- proj GEMM + fused rotation: tmp[512][1152] = s @ Wcat + bias
__global__ void proj_gemm_kernel(const float* __restrict__ s, const float* __restrict__ rot,
                                 const float* __restrict__ tran,
                                 const float* __restrict__ Wsq, const float* __restrict__ bsq,
                                 const float* __restrict__ Wsk, const float* __restrict__ bsk,
                                 const float* __restrict__ Wsv, const float* __restrict__ bsv,
                                 const float* __restrict__ Wpq, const float* __restrict__ bpq,
                                 const float* __restrict__ Wpk, const float* __restrict__ bpk,
                                 const float* __restrict__ Wpv, const float* __restrict__ bpv,
                                 float* __restrict__ tmp)
{
    int bx = blockIdx.x;            // 24 f-tiles of 48
    int n0 = blockIdx.y * 32;       // 16 n-tiles
    int f0 = bx * 48;
    const float* W; const float* bb; int dout; int segstart;
    if (bx < 4)       { W = Wsq; bb = bsq; dout = 192; segstart = 0; }
    else if (bx < 8)  { W = Wsk; bb = bsk; dout = 192; segstart = 192; }
    else if (bx < 12) { W = Wsv; bb = bsv; dout = 192; segstart = 384; }
    else if (bx < 15) { W = Wpq; bb = bpq; dout = 144; segstart = 576; }
    else if (bx < 18) { W = Wpk; bb = bpk; dout = 144; segstart = 720; }
    else              { W = Wpv; bb = bpv; dout = 288; segstart = 864; }
    int colbase = f0 - segstart;

    __shared__ float St[32][34];
    __shared__ float Ws[32][49];
    int tid = threadIdx.x;
    int ty = tid >> 4, tx = tid & 15;
    float acc[2][3] = {{0,0,0},{0,0,0}};

    for (int k0 = 0; k0 < CSD; k0 += 32) {
        {
            int r = tid >> 3, c4 = (tid & 7) * 4;
            float4 v = *(const float4*)&s[(size_t)(n0 + r) * CSD + k0 + c4];
            St[c4 + 0][r] = v.x; St[c4 + 1][r] = v.y; St[c4 + 2][r] = v.z; St[c4 + 3][r] = v.w;
        }
        for (int e = tid; e < 1536; e += 256) {
            int r = e / 48, c = e % 48;
            Ws[r][c] = W[(size_t)(k0 + r) * dout + colbase + c];
        }
        __syncthreads();
        #pragma unroll
        for (int k = 0; k < 32; k++) {
            float2 a = *(const float2*)&St[k][ty * 2];
            float b0 = Ws[k][tx * 3], b1 = Ws[k][tx * 3 + 1], b2 = Ws[k][tx * 3 + 2];
            acc[0][0] += a.x * b0; acc[0][1] += a.x * b1; acc[0][2] += a.x * b2;
            acc[1][0] += a.y * b0; acc[1][1] += a.y * b1; acc[1][2] += a.y * b2;
        }
        __syncthreads();
    }
    float bv0 = bb[colbase + tx * 3], bv1 = bb[colbase + tx * 3 + 1], bv2 = bb[colbase + tx * 3 + 2];
    #pragma unroll
    for (int r = 0; r < 2; r++) {
        int n = n0 + ty * 2 + r;
        float v0 = acc[r][0] + bv0, v1 = acc[r][1] + bv1, v2 = acc[r][2] + bv2;
        float* o = tmp + (size_t)n * TMPW + f0 + tx * 3;
        if (bx >= 12) {
            const float* R = rot + n * 9;
            const float* T = tran + n * 3;
            float g0 = R[0] * v0 + R[1] * v1 + R[2] * v2 + T[0];
            float g1 = R[3] * v0 + R[4] * v1 + R[5] * v2 + T[1];
            float g2 = R[6] * v0 + R[7] * v1 + R[8] * v2 + T[2];
            o[0] = g0; o[1] = g1; o[2] = g2;
        } else {
            o[0] = v0; o[1] = v1; o[2] = v2;
        }
    }
}

// ---------------- zcvt: pure streaming f32 -> bf16 convert of z (memcpy-shaped).
// grid-stride, 2048 blocks x 256 thr, no LDS, no barriers.
__global__ __launch_bounds__(256) void zcvt_kernel(const float* __restrict__ z,
                                                   ushort* __restrict__ z_bf)
{
    size_t idx = (size_t)blockIdx.x * 256 + threadIdx.x;
    const size_t total = (size_t)NN * NN * CZ / 8;     // 4194304 groups of 8
    const size_t stride = 2048 * 256;
    #pragma unroll 2
    for (size_t v = idx; v < total; v += stride) {
        float4 f0 = *(const float4*)&z[v * 8];
        float4 f1 = *(const float4*)&z[v * 8 + 4];
        BFU a;
        a.u[0] = f2bf(f0.x); a.u[1] = f2bf(f0.y); a.u[2] = f2bf(f0.z); a.u[3] = f2bf(f0.w);
        a.u[4] = f2bf(f1.x); a.u[5] = f2bf(f1.y); a.u[6] = f2bf(f1.z); a.u[7] = f2bf(f1.w);
        *(uint4*)&z_bf[v * 8] = a.q;
    }
}

// ---------------- augprep: build Qaug/Kaug [h][n][32] bf16 from tmp.
__global__ void augprep_kernel(const float* __restrict__ tmp,
                               const float* __restrict__ watt, const float* __restrict__ batt,
                               const float* __restrict__ tpw, const float* __restrict__ bsb,
                               ushort* __restrict__ Qaug, ushort* __restrict__ Kaug)
{
    int n = blockIdx.x;
    int tid = threadIdx.x;
    float w0 = watt[0], w1 = watt[1], w2 = watt[2], ba = batt[0];
    float A2 = w2 * ZW;
    __shared__ float nq[12], nk[12];
    if (tid < 24) {
        int h = tid >> 1, which = tid & 1;
        const float* p = tmp + (size_t)n * TMPW + (which ? 720 : 576) + h * 12;
        float s2 = 0.f;
        #pragma unroll
        for (int d = 0; d < 12; d++) s2 += p[d] * p[d];
        if (which) nk[h] = s2; else nq[h] = s2;
    }
    __syncthreads();

    for (int f = tid; f < 384; f += 256) {
        if (f < 192) {
            int h = f >> 4, k = f & 15;
            float sq = tmp[(size_t)n * TMPW + h * 16 + k] * (SW * w0);
            float sk = tmp[(size_t)n * TMPW + 192 + h * 16 + k];
            Qaug[((size_t)h * NN + n) * 32 + k] = f2bf(sq);
            Kaug[((size_t)h * NN + n) * 32 + k] = f2bf(sk);
        } else if (f < 336) {
            int e = f - 192; int h = e / 12, d = e % 12;
            float cpt = -0.5f * log1pf(expf(tpw[h])) * PW * w1;
            float pq = tmp[(size_t)n * TMPW + 576 + h * 12 + d];
            float pk = tmp[(size_t)n * TMPW + 720 + h * 12 + d];
            Qaug[((size_t)h * NN + n) * 32 + 16 + d] = f2bf(-2.f * cpt * pq);
            Kaug[((size_t)h * NN + n) * 32 + 16 + d] = f2bf(pk);
        } else {
            int e = f - 336; int h = e >> 2, sl = e & 3;
            float cpt = -0.5f * log1pf(expf(tpw[h])) * PW * w1;
            float qv, kv;
            if (sl == 0)      { qv = cpt * nq[h];      kv = 1.f; }
            else if (sl == 1) { qv = cpt;              kv = nk[h]; }
            else if (sl == 2) { qv = A2 * bsb[h] + ba; kv = 1.f; }
            else              { qv = 0.f;              kv = 0.f; }
            Qaug[((size_t)h * NN + n) * 32 + 28 + sl] = f2bf(qv);
            Kaug[((size_t)h * NN + n) * 32 + 28 + sl] = f2bf(kv);
        }
    }
}

// ---------------- zlogits: pair-bias via register MFMA, A-fragments loaded
// DIRECTLY from bf16 z_bf (no conversion). grid (4 jc, 512 i), block 256.
__global__ __launch_bounds__(256) void zlogits_kernel(const ushort* __restrict__ z_bf,
                                                      const float* __restrict__ resm,
                                                      const float* __restrict__ Wsb,
                                                      const float* __restrict__ watt,
                                                      ushort* __restrict__ lgts_bf)
{
    int jc = blockIdx.x;
    int i  = blockIdx.y;
    int tid = threadIdx.x;
    int w = tid >> 6, lane = tid & 63;
    int l16 = lane & 15, lhi = lane >> 4;
    float A2 = watt[2] * ZW;

    BFU breg[4];
    #pragma unroll
    for (int kk = 0; kk < 4; kk++) {
        #pragma unroll
        for (int e = 0; e < 8; e++) {
            int k = kk * 32 + lhi * 8 + e;
            float v = (l16 < HH) ? Wsb[k * HH + l16] * A2 : 0.f;
            breg[kk].u[e] = f2bf(v);
        }
    }

    float rmi = resm[i];
    int jbase = jc * 128 + w * 32;      // wave owns rows jbase..jbase+31

    const ushort* zb0 = z_bf + ((size_t)i * NN + jbase + l16) * CZ + lhi * 8;
    const ushort* zb1 = zb0 + (size_t)16 * CZ;
    BFU a[8];
    #pragma unroll
    for (int kk = 0; kk < 4; kk++) a[kk].q     = *(const uint4*)&zb0[kk * 32];
    #pragma unroll
    for (int kk = 0; kk < 4; kk++) a[4 + kk].q = *(const uint4*)&zb1[kk * 32];

    f32x4_t acc0 = {0.f, 0.f, 0.f, 0.f};
    f32x4_t acc1 = {0.f, 0.f, 0.f, 0.f};
    #pragma unroll
    for (int kk = 0; kk < 4; kk++)
        acc0 = __builtin_amdgcn_mfma_f32_16x16x32_bf16(a[kk].v, breg[kk].v, acc0, 0, 0, 0);
    #pragma unroll
    for (int kk = 0; kk < 4; kk++)
        acc1 = __builtin_amdgcn_mfma_f32_16x16x32_bf16(a[4 + kk].v, breg[kk].v, acc1, 0, 0, 0);

    if (l16 < HH) {
        ushort* lrow = lgts_bf + ((size_t)i * HH + l16) * NN;
        US4 o0, o1;
        #pragma unroll
        for (int r = 0; r < 4; r++) {
            int j0 = jbase + lhi * 4 + r;
            int j1 = j0 + 16;
            float lg0 = (rmi * resm[j0] == 0.f) ? MASK_NEG : acc0[r];
            float lg1 = (rmi * resm[j1] == 0.f) ? MASK_NEG : acc1[r];
            o0.us[r] = f2bf(lg0);
            o1.us[r] = f2bf(lg1);
        }
        *(uint2*)&lrow[jbase + lhi * 4]      = o0.u2;
        *(uint2*)&lrow[jbase + 16 + lhi * 4] = o1.u2;
    }
}

// ---------------- augsm: aug-GEMM (scalar+point+cb) + add pair lgts + softmax.
__global__ __launch_bounds__(256) void augsm_kernel(const ushort* __restrict__ lgts_bf,
                                                    const ushort* __restrict__ Qaug,
                                                    const ushort* __restrict__ Kaug,
                                                    ushort* __restrict__ attn_bf)
{
    int it = blockIdx.x;        // i-tile
    int h  = blockIdx.y;
    __shared__ float Dt[16][520];   // 33.3 KB
    int tid = threadIdx.x;
    int w = tid >> 6, lane = tid & 63;
    int l16 = lane & 15, lhi = lane >> 4;

    BFU a;
    a.q = *(const uint4*)&Qaug[(((size_t)h * NN) + it * 16 + l16) * 32 + lhi * 8];

    for (int jt = w; jt < 32; jt += 4) {
        BFU b;
        b.q = *(const uint4*)&Kaug[(((size_t)h * NN) + jt * 16 + l16) * 32 + lhi * 8];
        f32x4_t acc = {0.f, 0.f, 0.f, 0.f};
        acc = __builtin_amdgcn_mfma_f32_16x16x32_bf16(a.v, b.v, acc, 0, 0, 0);
        #pragma unroll
        for (int r = 0; r < 4; r++) Dt[lhi * 4 + r][jt * 16 + l16] = acc[r];
    }
    __syncthreads();

    #pragma unroll
    for (int rr = 0; rr < 4; rr++) {
        int row = w * 4 + rr;
        const ushort* lrow = lgts_bf + (((size_t)(it * 16 + row)) * HH + h) * NN;
        float v[8]; float m = -INFINITY;
        #pragma unroll
        for (int u = 0; u < 8; u++) {
            v[u] = bf2f(lrow[lane + 64 * u]) + Dt[row][lane + 64 * u];
            m = fmaxf(m, v[u]);
        }
        for (int off = 32; off; off >>= 1) m = fmaxf(m, __shfl_xor(m, off));
        float ssum = 0.f;
        #pragma unroll
        for (int u = 0; u < 8; u++) { v[u] = __expf(v[u] - m); ssum += v[u]; }
        for (int off = 32; off; off >>= 1) ssum += __shfl_xor(ssum, off);
        float inv = 1.f / ssum;
        ushort* ag = attn_bf + (((size_t)(it * 16 + row)) * HH + h) * NN;
        #pragma unroll
        for (int u = 0; u < 8; u++) ag[lane + 64 * u] = f2bf(v[u] * inv);
    }
}

// ---------------- rpair partials: grid (4 jq, 512 i); reads bf16 z_bf.
__global__ __launch_bounds__(256) void rpair_kernel(const ushort* __restrict__ z_bf,
                                                    const ushort* __restrict__ attn_bf,
                                                    float* __restrict__ part)
{
    int jq = blockIdx.x;
    int i  = blockIdx.y;
    __shared__ ushort pbf[128 * 12];
    __shared__ float pslab[4 * 12 * 128];
    int tid = threadIdx.x;

    if (tid < 192) {
        int h = tid >> 4, g = tid & 15;
        BFU v; v.q = *(const uint4*)&attn_bf[((size_t)i * HH + h) * NN + jq * 128 + g * 8];
        #pragma unroll
        for (int q = 0; q < 8; q++) pbf[(g * 8 + q) * 12 + h] = v.u[q];
    }
    __syncthreads();

    int w = tid >> 6, lane = tid & 63;
    int c0 = lane * 2;
    const ushort* zq = z_bf + ((size_t)i * NN + jq * 128 + w * 32) * CZ + c0;
    float acc[12][2];
    #pragma unroll
    for (int h = 0; h < 12; h++) { acc[h][0] = 0.f; acc[h][1] = 0.f; }

    #pragma unroll
    for (int j0 = 0; j0 < 32; j0 += 16) {
        uint zv[16];
        #pragma unroll
        for (int u = 0; u < 16; u++) zv[u] = *(const uint*)&zq[(size_t)(j0 + u) * CZ];
        #pragma unroll
        for (int u = 0; u < 16; u++) {
            float zx = bf2f((ushort)(zv[u] & 0xffff));
            float zy = bf2f((ushort)(zv[u] >> 16));
            int jl = w * 32 + j0 + u;
            const uint2* pr = (const uint2*)&pbf[jl * 12];
            uint2 pa = pr[0], pb2 = pr[1], pc = pr[2];
            float ph[12];
            ph[0]  = bf2f((ushort)(pa.x & 0xffff)); ph[1]  = bf2f((ushort)(pa.x >> 16));
            ph[2]  = bf2f((ushort)(pa.y & 0xffff)); ph[3]  = bf2f((ushort)(pa.y >> 16));
            ph[4]  = bf2f((ushort)(pb2.x & 0xffff)); ph[5]  = bf2f((ushort)(pb2.x >> 16));
            ph[6]  = bf2f((ushort)(pb2.y & 0xffff)); ph[7]  = bf2f((ushort)(pb2.y >> 16));
            ph[8]  = bf2f((ushort)(pc.x & 0xffff)); ph[9]  = bf2f((ushort)(pc.x >> 16));
            ph[10] = bf2f((ushort)(pc.y & 0xffff)); ph[11] = bf2f((ushort)(pc.y >> 16));
            #pragma unroll
            for (int h = 0; h < 12; h++) {
                acc[h][0] += ph[h] * zx;
                acc[h][1] += ph[h] * zy;
            }
        }
    }
    #pragma unroll
    for (int h = 0; h < 12; h++)
        *(float2*)&pslab[(w * 12 + h) * 128 + c0] = make_float2(acc[h][0], acc[h][1]);
    __syncthreads();

    for (int e = tid; e < 1536; e += 256) {
        float ssum = pslab[e] + pslab[1536 + e] + pslab[3072 + e] + pslab[4608 + e];
        part[((size_t)jq * NN + i) * 1536 + e] = ssum;
    }
}

// ---------------- per-head r_scalar + r_pt (+rotate back, norm) + combine rpair
__global__ void head_sum_kernel(const ushort* __restrict__ attn_bf, const float* __restrict__ tmp,
                                const float* __restrict__ rot, const float* __restrict__ tran,
                                const float* __restrict__ partR, float* __restrict__ cat)
{
    int i0 = blockIdx.x * 32;
    int h  = blockIdx.y;
    __shared__ float At[32][65];
    __shared__ float Sr[64][44];
    __shared__ float Rp[32][24];
    int tid = threadIdx.x;
    int il = tid & 31, fg = tid >> 5;
    float acc[5] = {0,0,0,0,0};

    for (int e = tid; e < 4096; e += 256) {
        int il2 = e >> 7, c = e & 127;
        size_t idx = (size_t)(i0 + il2) * 1536 + h * 128 + c;
        float ssum = partR[idx]
                   + partR[(size_t)NN * 1536 + idx]
                   + partR[(size_t)2 * NN * 1536 + idx]
                   + partR[(size_t)3 * NN * 1536 + idx];
        cat[(size_t)(i0 + il2) * CATDIM + h * CATH + 48 + c] = ssum;
    }

    for (int jc = 0; jc < NN; jc += 64) {
        {
            int r = tid >> 3, c8 = (tid & 7) * 8;
            const ushort* src = attn_bf + ((size_t)(i0 + r) * HH + h) * NN + jc + c8;
            BFU v; v.q = *(const uint4*)src;
            #pragma unroll
            for (int q = 0; q < 8; q++) At[r][c8 + q] = bf2f(v.u[q]);
        }
        {
            int jr = tid >> 2, d4 = (tid & 3) * 4;
            *(float4*)&Sr[jr][d4] = *(const float4*)&tmp[(size_t)(jc + jr) * TMPW + 384 + h * 16 + d4];
        }
        for (int e = tid; e < 384; e += 256) {
            int jr = e / 6, p4 = (e % 6) * 4;
            *(float4*)&Sr[jr][16 + p4] = *(const float4*)&tmp[(size_t)(jc + jr) * TMPW + 864 + h * 24 + p4];
        }
        __syncthreads();
        #pragma unroll 4
        for (int j = 0; j < 64; j++) {
            float a = At[il][j];
            #pragma unroll
            for (int q = 0; q < 5; q++) acc[q] += a * Sr[j][fg * 5 + q];
        }
        __syncthreads();
    }

    float* cbase = cat + (size_t)(i0 + il) * CATDIM + h * CATH;
    #pragma unroll
    for (int q = 0; q < 5; q++) {
        int f = fg * 5 + q;
        if (f < 16) cbase[f] = acc[q];
        else Rp[il][f - 16] = acc[q];
    }
    __syncthreads();

    {
        int il2 = tid >> 3, p = tid & 7;
        int i = i0 + il2;
        float gx = Rp[il2][p * 3 + 0] - tran[i * 3 + 0];
        float gy = Rp[il2][p * 3 + 1] - tran[i * 3 + 1];
        float gz = Rp[il2][p * 3 + 2] - tran[i * 3 + 2];
        const float* R = rot + i * 9;
        float lx = R[0] * gx + R[3] * gy + R[6] * gz;
        float ly = R[1] * gx + R[4] * gy + R[7] * gz;
        float lz = R[2] * gx + R[5] * gy + R[8] * gz;
        float nrm = sqrtf(lx * lx + ly * ly + lz * lz + 1e-8f);
        float* cp = cat + (size_t)i * CATDIM + h * CATH;
        cp[16 + p * 3 + 0] = lx; cp[16 + p * 3 + 1] = ly; cp[16 + p * 3 + 2] = lz;
        cp[40 + p] = nrm;
    }
}

// ---------------- out GEMM, K-split
__global__ void out_gemm_split_kernel(const float* __restrict__ cat, const float* __restrict__ Wout,
                                      float* __restrict__ part)
{
    int n0 = blockIdx.x * 64;
    int i0 = blockIdx.y * 64;
    int ks = blockIdx.z * KSPL;
    __shared__ float St[32][68];
    __shared__ float Bs[32][68];
    int tid = threadIdx.x;
    int ty = tid >> 4, tx = tid & 15;
    float acc[4][4] = {{0,0,0,0},{0,0,0,0},{0,0,0,0},{0,0,0,0}};

    for (int k0 = 0; k0 < KSPL; k0 += 32) {
        {
            int r = tid >> 2, c8 = (tid & 3) * 8;
            const float* src = cat + (size_t)(i0 + r) * CATDIM + ks + k0 + c8;
            float4 v0 = *(const float4*)src;
            float4 v1 = *(const float4*)(src + 4);
            St[c8+0][r]=v0.x; St[c8+1][r]=v0.y; St[c8+2][r]=v0.z; St[c8+3][r]=v0.w;
            St[c8+4][r]=v1.x; St[c8+5][r]=v1.y; St[c8+6][r]=v1.z; St[c8+7][r]=v1.w;
        }
        {
            int r = tid >> 3, c8 = (tid & 7) * 8;
            const float* src = Wout + (size_t)(ks + k0 + r) * CSD + n0 + c8;
            *(float4*)&Bs[r][c8]     = *(const float4*)src;
            *(float4*)&Bs[r][c8 + 4] = *(const float4*)(src + 4);
        }
        __syncthreads();
        #pragma unroll
        for (int k = 0; k < 32; k++) {
            float4 a = *(const float4*)&St[k][ty * 4];
            float4 b = *(const float4*)&Bs[k][tx * 4];
            float av[4] = {a.x, a.y, a.z, a.w};
            float bv[4] = {b.x, b.y, b.z, b.w};
            #pragma unroll
            for (int r = 0; r < 4; r++)
                #pragma unroll
                for (int c = 0; c < 4; c++) acc[r][c] += av[r] * bv[c];
        }
        __syncthreads();
    }
    #pragma unroll
    for (int r = 0; r < 4; r++) {
        float4 v = make_float4(acc[r][0], acc[r][1], acc[r][2], acc[r][3]);
        *(float4*)&part[((size_t)blockIdx.z * NN + i0 + ty * 4 + r) * CSD + n0 + tx * 4] = v;
    }
}

__global__ void reduce_out_kernel(const float* __restrict__ part, const float* __restrict__ bout,
                                  float* __restrict__ out)
{
    int v = blockIdx.x * 256 + threadIdx.x;
    int n4 = v % 96;
    float4 o = ((const float4*)bout)[n4];
    const float4* p4 = (const float4*)part;
    #pragma unroll
    for (int s = 0; s < NSPLIT; s++) {
        float4 t = p4[(size_t)s * 49152 + v];
        o.x += t.x; o.y += t.y; o.z += t.z; o.w += t.w;
    }
    ((float4*)out)[v] = o;
}

extern "C" void kernel_launch(void* const* d_in, const int* in_sizes, int n_in,
                              void* d_out, int out_size, void* d_ws, size_t ws_size,
                              hipStream_t stream) {
    const float* s    = (const float*)d_in[0];
    const float* z    = (const float*)d_in[1];
    const float* rot  = (const float*)d_in[2];
    const float* tran = (const float*)d_in[3];
    const float* resm = (const float*)d_in[4];
    const float* Wsq  = (const float*)d_in[5];  const float* bsq = (const float*)d_in[6];
    const float* Wsk  = (const float*)d_in[7];  const float* bsk = (const float*)d_in[8];
    const float* Wsv  = (const float*)d_in[9];  const float* bsv = (const float*)d_in[10];
    const float* Wsb  = (const float*)d_in[11]; const float* bsb = (const float*)d_in[12];
    const float* Wpq  = (const float*)d_in[13]; const float* bpq = (const float*)d_in[14];
    const float* Wpk  = (const float*)d_in[15]; const float* bpk = (const float*)d_in[16];
    const float* Wpv  = (const float*)d_in[17]; const float* bpv = (const float*)d_in[18];
    const float* watt = (const float*)d_in[19]; const float* batt = (const float*)d_in[20];
    const float* tpw  = (const float*)d_in[21];
    const float* Wout = (const float*)d_in[22]; const float* bout = (const float*)d_in[23];
    float* out = (float*)d_out;
    float* ws  = (float*)d_ws;

    float*  tmp     = ws;                        // 589824
    ushort* attn_bf = (ushort*)(ws + 589824);    // 1572864 f-slots
    ushort* lgts_bf = (ushort*)(ws + 2162688);   // 1572864 f-slots
    float*  partR   = ws + 3735552;              // 3145728
    ushort* Qaug    = (ushort*)(ws + 6881280);   // 98304 f-slots
    ushort* Kaug    = (ushort*)(ws + 6979584);   // 98304 f-slots
    float*  cat     = ws + 7077888;              // 1081344
    ushort* z_bf    = (ushort*)(ws + 8159232);   // 8388608 f-slots (67 MB)
    // partO aliases lgts_bf region (dead after head_sum reads are done... lgts dead after augsm)
    float*  partO   = ws + 2162688;              // 1179648 (fits in lgts_bf's 1572864)

    proj_gemm_kernel<<<dim3(24, 16), 256, 0, stream>>>(s, rot, tran,
                                                       Wsq, bsq, Wsk, bsk, Wsv, bsv,
                                                       Wpq, bpq, Wpk, bpk, Wpv, bpv, tmp);
    zcvt_kernel<<<2048, 256, 0, stream>>>(z, z_bf);
    augprep_kernel<<<512, 256, 0, stream>>>(tmp, watt, batt, tpw, bsb, Qaug, Kaug);
    zlogits_kernel<<<dim3(4, 512), 256, 0, stream>>>(z_bf, resm, Wsb, watt, lgts_bf);
    augsm_kernel<<<dim3(32, 12), 256, 0, stream>>>(lgts_bf, Qaug, Kaug, attn_bf);
    rpair_kernel<<<dim3(4, 512), 256, 0, stream>>>(z_bf, attn_bf, partR);
    head_sum_kernel<<<dim3(16, 12), 256, 0, stream>>>(attn_bf, tmp, rot, tran, partR, cat);
    out_gemm_split_kernel<<<dim3(6, 8, NSPLIT), 256, 0, stream>>>(cat, Wout, partO);
    reduce_out_kernel<<<192, 256, 0, stream>>>(partO, bout, out);
}

// Round 17
// 160.526 us; speedup vs baseline: 1.1794x; 1.1794x over previous
//
#include <hip/hip_runtime.h>
#include <hip/hip_bf16.h>
#include <math.h>

#define NN 512
#define CSD 384
#define CZ 128
#define HH 12
#define TMPW 1152          // 192 sq | 192 sk | 192 sv | 144 pq | 144 pk | 288 pv
#define CATH 176
#define CATDIM 2112
#define NSPLIT 6
#define KSPL 352

#define SW 0.14433756729740643f
#define PW 0.13608276348795434f
#define ZW 0.57735026918962576f
#define MASK_NEG -1.0e30f

typedef float f32x4_t __attribute__((ext_vector_type(4)));
typedef short bf16x8_t __attribute__((ext_vector_type(8)));

union BFU { uint4 q; bf16x8_t v; ushort u[8]; };

static __device__ __forceinline__ ushort f2bf(float f) {
    __hip_bfloat16 h = __float2bfloat16(f);
    return *reinterpret_cast<ushort*>(&h);
}
static __device__ __forceinline__ float bf2f(ushort u) {
    unsigned int v = ((unsigned int)u) << 16;
    return __uint_as_float(v);
}

// ---------------- proj GEMM + fused rotation: tmp[512][1152] = s @ Wcat + bias
__global__ void proj_gemm_kernel(const float* __restrict__ s, const float* __restrict__ rot,
                                 const float* __restrict__ tran,
                                 const float* __restrict__ Wsq, const float* __restrict__ bsq,
                                 const float* __restrict__ Wsk, const float* __restrict__ bsk,
                                 const float* __restrict__ Wsv, const float* __restrict__ bsv,
                                 const float* __restrict__ Wpq, const float* __restrict__ bpq,
                                 const float* __restrict__ Wpk, const float* __restrict__ bpk,
                                 const float* __restrict__ Wpv, const float* __restrict__ bpv,
                                 float* __restrict__ tmp)
{
    int bx = blockIdx.x;            // 24 f-tiles of 48
    int n0 = blockIdx.y * 32;       // 16 n-tiles
    int f0 = bx * 48;
    const float* W; const float* bb; int dout; int segstart;
    if (bx < 4)       { W = Wsq; bb = bsq; dout = 192; segstart = 0; }
    else if (bx < 8)  { W = Wsk; bb = bsk; dout = 192; segstart = 192; }
    else if (bx < 12) { W = Wsv; bb = bsv; dout = 192; segstart = 384; }
    else if (bx < 15) { W = Wpq; bb = bpq; dout = 144; segstart = 576; }
    else if (bx < 18) { W = Wpk; bb = bpk; dout = 144; segstart = 720; }
    else              { W = Wpv; bb = bpv; dout = 288; segstart = 864; }
    int colbase = f0 - segstart;

    __shared__ float St[32][34];
    __shared__ float Ws[32][49];
    int tid = threadIdx.x;
    int ty = tid >> 4, tx = tid & 15;
    float acc[2][3] = {{0,0,0},{0,0,0}};

    for (int k0 = 0; k0 < CSD; k0 += 32) {
        {
            int r = tid >> 3, c4 = (tid & 7) * 4;
            float4 v = *(const float4*)&s[(size_t)(n0 + r) * CSD + k0 + c4];
            St[c4 + 0][r] = v.x; St[c4 + 1][r] = v.y; St[c4 + 2][r] = v.z; St[c4 + 3][r] = v.w;
        }
        for (int e = tid; e < 1536; e += 256) {
            int r = e / 48, c = e % 48;
            Ws[r][c] = W[(size_t)(k0 + r) * dout + colbase + c];
        }
        __syncthreads();
        #pragma unroll
        for (int k = 0; k < 32; k++) {
            float2 a = *(const float2*)&St[k][ty * 2];
            float b0 = Ws[k][tx * 3], b1 = Ws[k][tx * 3 + 1], b2 = Ws[k][tx * 3 + 2];
            acc[0][0] += a.x * b0; acc[0][1] += a.x * b1; acc[0][2] += a.x * b2;
            acc[1][0] += a.y * b0; acc[1][1] += a.y * b1; acc[1][2] += a.y * b2;
        }
        __syncthreads();
    }
    float bv0 = bb[colbase + tx * 3], bv1 = bb[colbase + tx * 3 + 1], bv2 = bb[colbase + tx * 3 + 2];
    #pragma unroll
    for (int r = 0; r < 2; r++) {
        int n = n0 + ty * 2 + r;
        float v0 = acc[r][0] + bv0, v1 = acc[r][1] + bv1, v2 = acc[r][2] + bv2;
        float* o = tmp + (size_t)n * TMPW + f0 + tx * 3;
        if (bx >= 12) {
            const float* R = rot + n * 9;
            const float* T = tran + n * 3;
            float g0 = R[0] * v0 + R[1] * v1 + R[2] * v2 + T[0];
            float g1 = R[3] * v0 + R[4] * v1 + R[5] * v2 + T[1];
            float g2 = R[6] * v0 + R[7] * v1 + R[8] * v2 + T[2];
            o[0] = g0; o[1] = g1; o[2] = g2;
        } else {
            o[0] = v0; o[1] = v1; o[2] = v2;
        }
    }
}

// ---------------- augprep: build Qaug/Kaug [h][n][32] bf16 from tmp.
__global__ void augprep_kernel(const float* __restrict__ tmp,
                               const float* __restrict__ watt, const float* __restrict__ batt,
                               const float* __restrict__ tpw, const float* __restrict__ bsb,
                               ushort* __restrict__ Qaug, ushort* __restrict__ Kaug)
{
    int n = blockIdx.x;
    int tid = threadIdx.x;
    float w0 = watt[0], w1 = watt[1], w2 = watt[2], ba = batt[0];
    float A2 = w2 * ZW;
    __shared__ float nq[12], nk[12];
    if (tid < 24) {
        int h = tid >> 1, which = tid & 1;
        const float* p = tmp + (size_t)n * TMPW + (which ? 720 : 576) + h * 12;
        float s2 = 0.f;
        #pragma unroll
        for (int d = 0; d < 12; d++) s2 += p[d] * p[d];
        if (which) nk[h] = s2; else nq[h] = s2;
    }
    __syncthreads();

    for (int f = tid; f < 384; f += 256) {
        if (f < 192) {
            int h = f >> 4, k = f & 15;
            float sq = tmp[(size_t)n * TMPW + h * 16 + k] * (SW * w0);
            float sk = tmp[(size_t)n * TMPW + 192 + h * 16 + k];
            Qaug[((size_t)h * NN + n) * 32 + k] = f2bf(sq);
            Kaug[((size_t)h * NN + n) * 32 + k] = f2bf(sk);
        } else if (f < 336) {
            int e = f - 192; int h = e / 12, d = e % 12;
            float cpt = -0.5f * log1pf(expf(tpw[h])) * PW * w1;
            float pq = tmp[(size_t)n * TMPW + 576 + h * 12 + d];
            float pk = tmp[(size_t)n * TMPW + 720 + h * 12 + d];
            Qaug[((size_t)h * NN + n) * 32 + 16 + d] = f2bf(-2.f * cpt * pq);
            Kaug[((size_t)h * NN + n) * 32 + 16 + d] = f2bf(pk);
        } else {
            int e = f - 336; int h = e >> 2, sl = e & 3;
            float cpt = -0.5f * log1pf(expf(tpw[h])) * PW * w1;
            float qv, kv;
            if (sl == 0)      { qv = cpt * nq[h];      kv = 1.f; }
            else if (sl == 1) { qv = cpt;              kv = nk[h]; }
            else if (sl == 2) { qv = A2 * bsb[h] + ba; kv = 1.f; }
            else              { qv = 0.f;              kv = 0.f; }
            Qaug[((size_t)h * NN + n) * 32 + 28 + sl] = f2bf(qv);
            Kaug[((size_t)h * NN + n) * 32 + 28 + sl] = f2bf(kv);
        }
    }
}

// ---------------- sp: scalar+point+const logits via aug MFMA -> sp_bf[i][h][j] bf16
// grid (32 i-tiles, 12 h), block 256.
__global__ __launch_bounds__(256) void sp_kernel(const ushort* __restrict__ Qaug,
                                                 const ushort* __restrict__ Kaug,
                                                 ushort* __restrict__ sp_bf)
{
    int it = blockIdx.x;
    int h  = blockIdx.y;
    __shared__ float Dt[16][520];
    int tid = threadIdx.x;
    int w = tid >> 6, lane = tid & 63;
    int l16 = lane & 15, lhi = lane >> 4;

    BFU a;
    a.q = *(const uint4*)&Qaug[(((size_t)h * NN) + it * 16 + l16) * 32 + lhi * 8];

    for (int jt = w; jt < 32; jt += 4) {
        BFU b;
        b.q = *(const uint4*)&Kaug[(((size_t)h * NN) + jt * 16 + l16) * 32 + lhi * 8];
        f32x4_t acc = {0.f, 0.f, 0.f, 0.f};
        acc = __builtin_amdgcn_mfma_f32_16x16x32_bf16(a.v, b.v, acc, 0, 0, 0);
        #pragma unroll
        for (int r = 0; r < 4; r++) Dt[lhi * 4 + r][jt * 16 + l16] = acc[r];
    }
    __syncthreads();

    #pragma unroll
    for (int rr = 0; rr < 4; rr++) {
        int row = w * 4 + rr;
        ushort* sp = sp_bf + (((size_t)(it * 16 + row)) * HH + h) * NN;
        #pragma unroll
        for (int u = 0; u < 8; u++) sp[lane + 64 * u] = f2bf(Dt[row][lane + 64 * u]);
    }
}

// ---------------- flash: single z pass. grid (2 j-halves, 512 i), block 256 (4 waves).
// Per 64-j tile: pair MFMA (z regs) + sp -> logits (LDS) -> online max -> p -> r_pair acc.
// Outputs: e_bf[jh][i][h][256] = exp(lg - m_half), m_arr, partR (unnormalized r_pair).
__global__ __launch_bounds__(256) void flash_kernel(const float* __restrict__ z,
                                                    const float* __restrict__ resm,
                                                    const float* __restrict__ Wsb,
                                                    const float* __restrict__ watt,
                                                    const ushort* __restrict__ sp_bf,
                                                    ushort* __restrict__ e_bf,
                                                    float* __restrict__ partR,
                                                    float* __restrict__ m_arr)
{
    int jh = blockIdx.x;
    int i  = blockIdx.y;
    __shared__ float lt[256 * 13];          // logits [local j][h], 13.3 KB
    __shared__ float p_lds[64 * 13];        // per-tile p
    __shared__ ushort sp_lds[12 * 260];     // sp slice [h][256]
    __shared__ float mtile[4][12];
    __shared__ float mrun[12];
    __shared__ float scale_s[12];
    int tid = threadIdx.x;
    int w = tid >> 6, lane = tid & 63;
    int l16 = lane & 15, lhi = lane >> 4;
    float A2 = watt[2] * ZW;

    BFU breg[4];
    #pragma unroll
    for (int kk = 0; kk < 4; kk++) {
        #pragma unroll
        for (int e = 0; e < 8; e++) {
            int k = kk * 32 + lhi * 8 + e;
            float v = (l16 < HH) ? Wsb[k * HH + l16] * A2 : 0.f;
            breg[kk].u[e] = f2bf(v);
        }
    }

    for (int e = tid; e < 768; e += 256) {
        int h = e >> 6, q = e & 63;
        *(uint2*)&sp_lds[h * 260 + q * 4] =
            *(const uint2*)&sp_bf[((size_t)i * HH + h) * NN + jh * 256 + q * 4];
    }
    if (tid < 12) mrun[tid] = -INFINITY;

    int hg = tid >> 7, c = tid & 127;
    float acc[6] = {0, 0, 0, 0, 0, 0};
    float rmi = resm[i];
    __syncthreads();

    for (int t4 = 0; t4 < 4; t4++) {
        int jloc = t4 * 64 + w * 16;            // wave's local row base (0..255)
        int jglob = jh * 256 + jloc;
        // pair MFMA: lane loads row jglob + l16
        const float* zr = z + ((size_t)i * NN + jglob + l16) * CZ + lhi * 8;
        float4 pr[8];
        #pragma unroll
        for (int kk = 0; kk < 4; kk++) {
            pr[kk * 2]     = *(const float4*)&zr[kk * 32];
            pr[kk * 2 + 1] = *(const float4*)&zr[kk * 32 + 4];
        }
        f32x4_t a4 = {0.f, 0.f, 0.f, 0.f};
        #pragma unroll
        for (int kk = 0; kk < 4; kk++) {
            float4 f0 = pr[kk * 2], f1 = pr[kk * 2 + 1];
            BFU a;
            a.u[0] = f2bf(f0.x); a.u[1] = f2bf(f0.y); a.u[2] = f2bf(f0.z); a.u[3] = f2bf(f0.w);
            a.u[4] = f2bf(f1.x); a.u[5] = f2bf(f1.y); a.u[6] = f2bf(f1.z); a.u[7] = f2bf(f1.w);
            a4 = __builtin_amdgcn_mfma_f32_16x16x32_bf16(a.v, breg[kk].v, a4, 0, 0, 0);
        }
        // logits + wave max (h = l16, j = jloc + lhi*4 + r)
        if (l16 < HH) {
            float mw = -INFINITY;
            #pragma unroll
            for (int r = 0; r < 4; r++) {
                int jl = jloc + lhi * 4 + r;
                float sp = bf2f(sp_lds[l16 * 260 + jl]);
                float lg = a4[r] + sp;
                if (rmi * resm[jh * 256 + jl] == 0.f) lg = MASK_NEG;
                lt[jl * 13 + l16] = lg;
                mw = fmaxf(mw, lg);
            }
            mw = fmaxf(mw, __shfl_xor(mw, 16));
            mw = fmaxf(mw, __shfl_xor(mw, 32));
            if (lhi == 0) mtile[w][l16] = mw;
        }
        __syncthreads();
        if (tid < 12) {
            float mo = mrun[tid];
            float mn = fmaxf(mo, fmaxf(fmaxf(mtile[0][tid], mtile[1][tid]),
                                       fmaxf(mtile[2][tid], mtile[3][tid])));
            scale_s[tid] = (mo == -INFINITY) ? 0.f : __expf(mo - mn);
            mrun[tid] = mn;
        }
        __syncthreads();
        // p for this tile + rescale accumulators
        for (int e = tid; e < 768; e += 256) {
            int jl = e & 63, h = e >> 6;
            p_lds[jl * 13 + h] = __expf(lt[(t4 * 64 + jl) * 13 + h] - mrun[h]);
        }
        #pragma unroll
        for (int q = 0; q < 6; q++) acc[q] *= scale_s[hg * 6 + q];
        __syncthreads();
        // accumulate r_pair: z re-read (L2-hot), lane owns channel c, heads hg*6..+5
        const float* z2 = z + ((size_t)i * NN + jh * 256 + t4 * 64) * CZ + c;
        #pragma unroll 4
        for (int jl = 0; jl < 64; jl++) {
            float zv = z2[(size_t)jl * CZ];
            #pragma unroll
            for (int q = 0; q < 6; q++) acc[q] += p_lds[jl * 13 + hg * 6 + q] * zv;
        }
        __syncthreads();
    }

    // epilogue: e = exp(lt - m_half) -> e_bf; m; partR
    for (int e = tid; e < 3072; e += 256) {
        int jl = e & 255, h = e >> 8;
        float ev = __expf(lt[jl * 13 + h] - mrun[h]);
        e_bf[(((size_t)jh * NN + i) * HH + h) * 256 + jl] = f2bf(ev);
    }
    if (tid < 12) m_arr[((size_t)jh * NN + i) * HH + tid] = mrun[tid];
    #pragma unroll
    for (int q = 0; q < 6; q++)
        partR[(((size_t)jh * NN + i) * HH + hg * 6 + q) * 128 + c] = acc[q];
}

// ---------------- combine: merge halves -> final attn_bf + cat pair channels.
__global__ __launch_bounds__(256) void combine_kernel(const ushort* __restrict__ e_bf,
                                                      const float* __restrict__ m_arr,
                                                      const float* __restrict__ partR,
                                                      ushort* __restrict__ attn_bf,
                                                      float* __restrict__ cat)
{
    int i = blockIdx.x;
    __shared__ float sA[12], sB[12], invl[12];
    int tid = threadIdx.x;
    int w = tid >> 6, lane = tid & 63;

    #pragma unroll
    for (int t = 0; t < 3; t++) {
        int h = w * 3 + t;
        float m0 = m_arr[((size_t)i) * HH + h];
        float m1 = m_arr[((size_t)NN + i) * HH + h];
        float m = fmaxf(m0, m1);
        float s0 = __expf(m0 - m), s1 = __expf(m1 - m);
        const ushort* e0 = e_bf + (((size_t)i) * HH + h) * 256;
        const ushort* e1 = e_bf + (((size_t)NN + i) * HH + h) * 256;
        float v0[4], v1[4]; float sum = 0.f;
        #pragma unroll
        for (int u = 0; u < 4; u++) {
            v0[u] = bf2f(e0[lane + 64 * u]);
            v1[u] = bf2f(e1[lane + 64 * u]);
            sum += v0[u] * s0 + v1[u] * s1;
        }
        for (int off = 32; off; off >>= 1) sum += __shfl_xor(sum, off);
        float inv = 1.f / sum;
        ushort* ag = attn_bf + ((size_t)i * HH + h) * NN;
        #pragma unroll
        for (int u = 0; u < 4; u++) {
            ag[lane + 64 * u]       = f2bf(v0[u] * s0 * inv);
            ag[256 + lane + 64 * u] = f2bf(v1[u] * s1 * inv);
        }
        if (lane == 0) { sA[h] = s0; sB[h] = s1; invl[h] = inv; }
    }
    __syncthreads();

    for (int e = tid; e < 1536; e += 256) {
        int h = e >> 7, c = e & 127;
        float v = (partR[(((size_t)i) * HH + h) * 128 + c] * sA[h]
                 + partR[(((size_t)NN + i) * HH + h) * 128 + c] * sB[h]) * invl[h];
        cat[(size_t)i * CATDIM + h * CATH + 48 + c] = v;
    }
}

// ---------------- per-head r_scalar + r_pt (+rotate back, norm); attn bf16
__global__ void head_sum_kernel(const ushort* __restrict__ attn_bf, const float* __restrict__ tmp,
                                const float* __restrict__ rot, const float* __restrict__ tran,
                                float* __restrict__ cat)
{
    int i0 = blockIdx.x * 32;
    int h  = blockIdx.y;
    __shared__ float At[32][65];
    __shared__ float Sr[64][44];
    __shared__ float Rp[32][24];
    int tid = threadIdx.x;
    int il = tid & 31, fg = tid >> 5;
    float acc[5] = {0,0,0,0,0};

    for (int jc = 0; jc < NN; jc += 64) {
        {
            int r = tid >> 3, c8 = (tid & 7) * 8;
            const ushort* src = attn_bf + ((size_t)(i0 + r) * HH + h) * NN + jc + c8;
            BFU v; v.q = *(const uint4*)src;
            #pragma unroll
            for (int q = 0; q < 8; q++) At[r][c8 + q] = bf2f(v.u[q]);
        }
        {
            int jr = tid >> 2, d4 = (tid & 3) * 4;
            *(float4*)&Sr[jr][d4] = *(const float4*)&tmp[(size_t)(jc + jr) * TMPW + 384 + h * 16 + d4];
        }
        for (int e = tid; e < 384; e += 256) {
            int jr = e / 6, p4 = (e % 6) * 4;
            *(float4*)&Sr[jr][16 + p4] = *(const float4*)&tmp[(size_t)(jc + jr) * TMPW + 864 + h * 24 + p4];
        }
        __syncthreads();
        #pragma unroll 4
        for (int j = 0; j < 64; j++) {
            float a = At[il][j];
            #pragma unroll
            for (int q = 0; q < 5; q++) acc[q] += a * Sr[j][fg * 5 + q];
        }
        __syncthreads();
    }

    float* cbase = cat + (size_t)(i0 + il) * CATDIM + h * CATH;
    #pragma unroll
    for (int q = 0; q < 5; q++) {
        int f = fg * 5 + q;
        if (f < 16) cbase[f] = acc[q];
        else Rp[il][f - 16] = acc[q];
    }
    __syncthreads();

    {
        int il2 = tid >> 3, p = tid & 7;
        int i = i0 + il2;
        float gx = Rp[il2][p * 3 + 0] - tran[i * 3 + 0];
        float gy = Rp[il2][p * 3 + 1] - tran[i * 3 + 1];
        float gz = Rp[il2][p * 3 + 2] - tran[i * 3 + 2];
        const float* R = rot + i * 9;
        float lx = R[0] * gx + R[3] * gy + R[6] * gz;
        float ly = R[1] * gx + R[4] * gy + R[7] * gz;
        float lz = R[2] * gx + R[5] * gy + R[8] * gz;
        float nrm = sqrtf(lx * lx + ly * ly + lz * lz + 1e-8f);
        float* cp = cat + (size_t)i * CATDIM + h * CATH;
        cp[16 + p * 3 + 0] = lx; cp[16 + p * 3 + 1] = ly; cp[16 + p * 3 + 2] = lz;
        cp[40 + p] = nrm;
    }
}

// ---------------- out GEMM, K-split
__global__ void out_gemm_split_kernel(const float* __restrict__ cat, const float* __restrict__ Wout,
                                      float* __restrict__ part)
{
    int n0 = blockIdx.x * 64;
    int i0 = blockIdx.y * 64;
    int ks = blockIdx.z * KSPL;
    __shared__ float St[32][68];
    __shared__ float Bs[32][68];
    int tid = threadIdx.x;
    int ty = tid >> 4, tx = tid & 15;
    float acc[4][4] = {{0,0,0,0},{0,0,0,0},{0,0,0,0},{0,0,0,0}};

    for (int k0 = 0; k0 < KSPL; k0 += 32) {
        {
            int r = tid >> 2, c8 = (tid & 3) * 8;
            const float* src = cat + (size_t)(i0 + r) * CATDIM + ks + k0 + c8;
            float4 v0 = *(const float4*)src;
            float4 v1 = *(const float4*)(src + 4);
            St[c8+0][r]=v0.x; St[c8+1][r]=v0.y; St[c8+2][r]=v0.z; St[c8+3][r]=v0.w;
            St[c8+4][r]=v1.x; St[c8+5][r]=v1.y; St[c8+6][r]=v1.z; St[c8+7][r]=v1.w;
        }
        {
            int r = tid >> 3, c8 = (tid & 7) * 8;
            const float* src = Wout + (size_t)(ks + k0 + r) * CSD + n0 + c8;
            *(float4*)&Bs[r][c8]     = *(const float4*)src;
            *(float4*)&Bs[r][c8 + 4] = *(const float4*)(src + 4);
        }
        __syncthreads();
        #pragma unroll
        for (int k = 0; k < 32; k++) {
            float4 a = *(const float4*)&St[k][ty * 4];
            float4 b = *(const float4*)&Bs[k][tx * 4];
            float av[4] = {a.x, a.y, a.z, a.w};
            float bv[4] = {b.x, b.y, b.z, b.w};
            #pragma unroll
            for (int r = 0; r < 4; r++)
                #pragma unroll
                for (int c = 0; c < 4; c++) acc[r][c] += av[r] * bv[c];
        }
        __syncthreads();
    }
    #pragma unroll
    for (int r = 0; r < 4; r++) {
        float4 v = make_float4(acc[r][0], acc[r][1], acc[r][2], acc[r][3]);
        *(float4*)&part[((size_t)blockIdx.z * NN + i0 + ty * 4 + r) * CSD + n0 + tx * 4] = v;
    }
}

__global__ void reduce_out_kernel(const float* __restrict__ part, const float* __restrict__ bout,
                                  float* __restrict__ out)
{
    int v = blockIdx.x * 256 + threadIdx.x;
    int n4 = v % 96;
    float4 o = ((const float4*)bout)[n4];
    const float4* p4 = (const float4*)part;
    #pragma unroll
    for (int s = 0; s < NSPLIT; s++) {
        float4 t = p4[(size_t)s * 49152 + v];
        o.x += t.x; o.y += t.y; o.z += t.z; o.w += t.w;
    }
    ((float4*)out)[v] = o;
}

extern "C" void kernel_launch(void* const* d_in, const int* in_sizes, int n_in,
                              void* d_out, int out_size, void* d_ws, size_t ws_size,
                              hipStream_t stream) {
    const float* s    = (const float*)d_in[0];
    const float* z    = (const float*)d_in[1];
    const float* rot  = (const float*)d_in[2];
    const float* tran = (const float*)d_in[3];
    const float* resm = (const float*)d_in[4];
    const float* Wsq  = (const float*)d_in[5];  const float* bsq = (const float*)d_in[6];
    const float* Wsk  = (const float*)d_in[7];  const float* bsk = (const float*)d_in[8];
    const float* Wsv  = (const float*)d_in[9];  const float* bsv = (const float*)d_in[10];
    const float* Wsb  = (const float*)d_in[11]; const float* bsb = (const float*)d_in[12];
    const float* Wpq  = (const float*)d_in[13]; const float* bpq = (const float*)d_in[14];
    const float* Wpk  = (const float*)d_in[15]; const float* bpk = (const float*)d_in[16];
    const float* Wpv  = (const float*)d_in[17]; const float* bpv = (const float*)d_in[18];
    const float* watt = (const float*)d_in[19]; const float* batt = (const float*)d_in[20];
    const float* tpw  = (const float*)d_in[21];
    const float* Wout = (const float*)d_in[22]; const float* bout = (const float*)d_in[23];
    float* out = (float*)d_out;
    float* ws  = (float*)d_ws;

    float*  tmp     = ws;                        // 589824
    ushort* attn_bf = (ushort*)(ws + 589824);    // 1572864 f-slots
    ushort* sp_bf   = (ushort*)(ws + 2162688);   // 1572864 f-slots
    ushort* e_bf    = (ushort*)(ws + 3735552);   // 1572864 f-slots
    float*  partR   = ws + 5308416;              // 1572864
    float*  m_arr   = ws + 6881280;              // 12288
    ushort* Qaug    = (ushort*)(ws + 6893568);   // 98304 f-slots
    ushort* Kaug    = (ushort*)(ws + 6991872);   // 98304 f-slots
    float*  cat     = ws + 7090176;              // 1081344
    float*  partO   = ws + 8171520;              // 1179648

    proj_gemm_kernel<<<dim3(24, 16), 256, 0, stream>>>(s, rot, tran,
                                                       Wsq, bsq, Wsk, bsk, Wsv, bsv,
                                                       Wpq, bpq, Wpk, bpk, Wpv, bpv, tmp);
    augprep_kernel<<<512, 256, 0, stream>>>(tmp, watt, batt, tpw, bsb, Qaug, Kaug);
    sp_kernel<<<dim3(32, 12), 256, 0, stream>>>(Qaug, Kaug, sp_bf);
    flash_kernel<<<dim3(2, 512), 256, 0, stream>>>(z, resm, Wsb, watt, sp_bf,
                                                   e_bf, partR, m_arr);
    combine_kernel<<<512, 256, 0, stream>>>(e_bf, m_arr, partR, attn_bf, cat);
    head_sum_kernel<<<dim3(16, 12), 256, 0, stream>>>(attn_bf, tmp, rot, tran, cat);
    out_gemm_split_kernel<<<dim3(6, 8, NSPLIT), 256, 0, stream>>>(cat, Wout, partO);
    reduce_out_kernel<<<192, 256, 0, stream>>>(partO, bout, out);
}